// Round 19
// baseline (75.245 us; speedup 1.0000x reference)
//
#include <hip/hip_runtime.h>
#include <math.h>

#define NCLS 80
#define TOPK 1000
#define CAND_CAP 4096
#define PAY_CAP 2048
#define TRI_IDX(f, g) ((f) * 16 - ((f) * ((f) - 1)) / 2 + ((g) - (f)))

// Correctly-rounded float sigmoid: matches numpy's 1/(1+np.exp(-x)) bit-for-bit.
__device__ __forceinline__ float sigmoid_np(float x) {
  float e = (float)exp(-(double)x);
  return 1.0f / (1.0f + e);
}
__device__ __forceinline__ float exp_np(float x) { return (float)exp((double)x); }

__device__ __forceinline__ unsigned fkey(float s) {
  unsigned u = __float_as_uint(s);
  return ((int)u < 0) ? ~u : (u | 0x80000000u);
}

// Scores are sigmoid(max of 80 logits) in (0.5, 1): float exponent constant,
// all ordering in the mantissa. 4096 bins on mantissa bits [22:11].
#define KEY_BASE 0xBF000000u
__device__ __forceinline__ unsigned kbin(unsigned key) { return (key >> 11) & 0xFFFu; }

// Wave-aggregated LDS histogram add: one atomic per distinct bin per wave.
__device__ __forceinline__ void agg_add(unsigned* h, unsigned bin, bool pred) {
  unsigned long long rem = __ballot(pred);
  const int lane = threadIdx.x & 63;
  while (rem) {
    int leader = __ffsll(rem) - 1;
    unsigned lb = (unsigned)__shfl((int)bin, leader, 64);
    unsigned long long m = __ballot(pred && bin == lb);
    if (lane == leader) atomicAdd(&h[lb], (unsigned)__popcll(m));
    rem &= ~m;
  }
}

__global__ void k_zero(unsigned* __restrict__ p, int nwords) {
  int i = blockIdx.x * 256 + threadIdx.x;
  if (i < nwords) p[i] = 0u;
}

// 4 lanes per anchor; argmax on raw logits; one exact sigmoid per anchor;
// per-block LDS hist of mantissa[22:11], nonzero bins merged to ghist1.
__launch_bounds__(1024)
__global__ void k_score(const float* __restrict__ cls, float* __restrict__ scores,
                        int* __restrict__ labels, unsigned* __restrict__ ghist1, int M) {
  __shared__ unsigned h1[4096];
  const int t = threadIdx.x;
  #pragma unroll
  for (int k = 0; k < 4; ++k) h1[t + 1024 * k] = 0u;
  __syncthreads();

  int gid = blockIdx.x * 1024 + t;
  int anchor = gid >> 2;
  int q = gid & 3;
  bool act = anchor < M;
  float lv[20];
  float best = -3.4e38f; int bc = 0;
  if (act) {
    const float4* row = reinterpret_cast<const float4*>(cls) + (size_t)anchor * (NCLS / 4);
    #pragma unroll
    for (int k = 0; k < 5; ++k) {
      float4 v = row[q + 4 * k];
      int cbase = (q + 4 * k) * 4;
      lv[4 * k + 0] = v.x; lv[4 * k + 1] = v.y; lv[4 * k + 2] = v.z; lv[4 * k + 3] = v.w;
      if (v.x > best) { best = v.x; bc = cbase + 0; }
      if (v.y > best) { best = v.y; bc = cbase + 1; }
      if (v.z > best) { best = v.z; bc = cbase + 2; }
      if (v.w > best) { best = v.w; bc = cbase + 3; }
    }
  } else {
    #pragma unroll
    for (int k = 0; k < 20; ++k) lv[k] = -3.4e38f;
  }
  #pragma unroll
  for (int d = 1; d < 4; d <<= 1) {
    float ob = __shfl_xor(best, d, 64);
    int oc = __shfl_xor(bc, d, 64);
    if (ob > best || (ob == best && oc < bc)) { best = ob; bc = oc; }
  }
  float s = sigmoid_np(best);
  float sp = s * (1.0f - s);
  float band = (s < 1.0f && sp > 0.0f) ? (4.8e-7f / sp) : 3.4e38f;  // 8 ulps margin
  float thresh = best - band;
  int cclose = 1 << 30;
  #pragma unroll
  for (int k = 0; k < 5; ++k) {
    #pragma unroll
    for (int j = 0; j < 4; ++j) {
      int c = (q + 4 * k) * 4 + j;
      if (lv[4 * k + j] >= thresh && c < cclose) cclose = c;
    }
  }
  #pragma unroll
  for (int d = 1; d < 4; d <<= 1) {
    int oc = __shfl_xor(cclose, d, 64);
    if (oc < cclose) cclose = oc;
  }
  int lab = bc;
  if (act && cclose < bc && q == 0) {  // rare exact fallback
    float bp = -1.0f; int bl = 0;
    for (int c = 0; c < NCLS; ++c) {
      float p = sigmoid_np(cls[(size_t)anchor * NCLS + c]);
      if (p > bp) { bp = p; bl = c; }
    }
    lab = bl;
  }
  unsigned key = fkey(s);
  if (act && q == 0) {
    scores[anchor] = s;
    labels[anchor] = lab;
  }
  agg_add(h1, kbin(key), act && q == 0 && key >= KEY_BASE);
  __syncthreads();
  #pragma unroll
  for (int k = 0; k < 4; ++k) {
    unsigned c = h1[t + 1024 * k];
    if (c) atomicAdd(&ghist1[t + 1024 * k], c);
  }
}

// Multi-block compact with FAT RECORDS (R18 lesson: k_maskr's 16x replicated
// scattered reg/labels gathers were 897KB of FETCH; gather ONCE here where
// each candidate is touched anyway, spread over 13 overlapping blocks).
__launch_bounds__(1024)
__global__ void k_compact(const unsigned* __restrict__ ghist1, const float* __restrict__ scores,
                          const int* __restrict__ labels, const float* __restrict__ reg,
                          unsigned long long* __restrict__ cand,
                          float4* __restrict__ candp, int* __restrict__ candl,
                          unsigned* __restrict__ gcount, int M) {
  __shared__ unsigned chunks[1024];
  __shared__ int sB1;
  __shared__ unsigned wcnt[16];
  __shared__ unsigned sbase;
  const int t = threadIdx.x;
  const int lane = t & 63, wid = t >> 6;
  if (t == 0) sB1 = 0;

  unsigned hb0 = ghist1[4 * t], hb1 = ghist1[4 * t + 1],
           hb2 = ghist1[4 * t + 2], hb3 = ghist1[4 * t + 3];
  chunks[t] = hb0 + hb1 + hb2 + hb3;
  __syncthreads();
  for (int d = 1; d < 1024; d <<= 1) {
    unsigned v = chunks[t] + ((t + d < 1024) ? chunks[t + d] : 0u);
    __syncthreads(); chunks[t] = v; __syncthreads();
  }
  {
    unsigned ssc = chunks[t];
    unsigned ssn = (t + 1 < 1024) ? chunks[t + 1] : 0u;
    if (ssc >= (unsigned)TOPK && ssn < (unsigned)TOPK) {
      unsigned hb[4] = {hb0, hb1, hb2, hb3};
      unsigned run = ssn;
      for (int b = 3; b >= 0; --b) {
        run += hb[b];
        if (run >= (unsigned)TOPK) { sB1 = 4 * t + b; break; }
      }
    }
  }
  __syncthreads();
  const unsigned T = KEY_BASE + ((unsigned)sB1 << 11);

  int base = (blockIdx.x * 1024 + t) * 4;
  unsigned keys[4]; int idxs[4]; int np = 0;
  if (base + 3 < M) {
    float4 v = *reinterpret_cast<const float4*>(scores + base);
    unsigned kk[4] = {fkey(v.x), fkey(v.y), fkey(v.z), fkey(v.w)};
    #pragma unroll
    for (int j = 0; j < 4; ++j)
      if (kk[j] >= T) { keys[np] = kk[j]; idxs[np] = base + j; ++np; }
  } else {
    for (int i = base; i < M; ++i) {
      unsigned key = fkey(scores[i]);
      if (key >= T) { keys[np] = key; idxs[np] = i; ++np; }
    }
  }
  int sc = np;
  #pragma unroll
  for (int d = 1; d < 64; d <<= 1) {
    int o = __shfl_up(sc, d, 64);
    if (lane >= d) sc += o;
  }
  if (lane == 63) wcnt[wid] = (unsigned)sc;
  __syncthreads();
  if (t == 0) {
    unsigned acc = 0;
    for (int w = 0; w < 16; ++w) { unsigned v = wcnt[w]; wcnt[w] = acc; acc += v; }
    sbase = acc ? atomicAdd(gcount, acc) : 0u;
  }
  __syncthreads();
  unsigned pos = sbase + wcnt[wid] + (unsigned)(sc - np);
  for (int j = 0; j < np; ++j) {
    if (pos < (unsigned)CAND_CAP) {
      int idx = idxs[j];
      cand[pos] = ((unsigned long long)keys[j] << 32) | (unsigned)(~(unsigned)idx);
      candp[pos] = *reinterpret_cast<const float4*>(reg + (size_t)idx * 4);
      candl[pos] = labels[idx];
    }
    ++pos;
  }
}

// 16-block mask with replicated rank+decode from CONTIGUOUS fat records
// (no scattered gathers). Block 0 publishes sel_*/boxes for k_nms.
__launch_bounds__(1024)
__global__ void k_maskr(const unsigned long long* __restrict__ cand,
                        const float4* __restrict__ candp, const int* __restrict__ candl,
                        const unsigned* __restrict__ gcount,
                        const float* __restrict__ asz, const int* __restrict__ pW, int A,
                        float* __restrict__ sel_score, int* __restrict__ sel_label,
                        float* __restrict__ boxes,
                        unsigned long long* __restrict__ maskC) {
  __shared__ unsigned long long ck[CAND_CAP];   // 32KB
  __shared__ float4 pay[PAY_CAP];               // 32KB
  __shared__ int payl[PAY_CAP];                 // 8KB
  __shared__ float so0[1024], so1[1024], so2[1024], so3[1024], sa[1024];  // 20KB
  __shared__ float4 bx[1024];                   // 16KB
  __shared__ float ssc[1024]; __shared__ int slab[1024];  // 8KB
  const int t = threadIdx.x;
  const int c = blockIdx.x;

  ssc[t] = 0.0f; slab[t] = 0;
  so0[t] = 0.0f; so1[t] = 0.0f; so2[t] = 0.0f; so3[t] = 0.0f; sa[t] = 0.0f;
  unsigned n = *gcount; if (n > (unsigned)CAND_CAP) n = (unsigned)CAND_CAP;
  unsigned npay = n < (unsigned)PAY_CAP ? n : (unsigned)PAY_CAP;
  for (int i = t; i < (int)n; i += 1024) ck[i] = cand[i];
  for (int i = t; i < (int)npay; i += 1024) { pay[i] = candp[i]; payl[i] = candl[i]; }
  __syncthreads();

  // rank + decode (replicated per block; ~n LDS-broadcast compares/thread)
  for (int cc = 0; cc < CAND_CAP; cc += 1024) {
    if ((unsigned)cc >= n) break;
    int cidx = cc + t;
    bool actv = (unsigned)cidx < n;
    unsigned long long my = actv ? ck[cidx] : 0ull;
    int r = 0;
    for (int j = 0; j < (int)n; ++j) r += (ck[j] > my);
    if (actv && r < TOPK) {
      unsigned key = (unsigned)(my >> 32);
      unsigned u = (key & 0x80000000u) ? (key ^ 0x80000000u) : ~key;
      float scv = __uint_as_float(u);
      int idx = (int)(~(unsigned)my);
      int lab = (cidx < (int)npay) ? payl[cidx] : candl[cidx];
      float4 rg = (cidx < (int)npay) ? pay[cidx] : candp[cidx];
      int W = *pW;
      int a = idx % A;
      int cell = idx / A;
      int x = cell % W;
      int y = cell / W;
      float aw = asz[a * 2 + 0], ah = asz[a * 2 + 1];
      float ax = ((float)x + 0.5f) * 32.0f;
      float ay = ((float)y + 0.5f) * 32.0f;
      float offx = fminf(fmaxf(rg.x * aw, -32.0f), 32.0f);
      float offy = fminf(fmaxf(rg.y * ah, -32.0f), 32.0f);
      float cx = ax + offx, cy = ay + offy;
      const float SC = 4.135166556742356f;  // log(1000/16)
      float bw = aw * exp_np(fminf(rg.z, SC));
      float bh = ah * exp_np(fminf(rg.w, SC));
      float x1 = cx - 0.5f * bw, y1 = cy - 0.5f * bh;
      float x2 = cx + 0.5f * bw, y2 = cy + 0.5f * bh;
      float off = (float)lab * 100000.0f;
      float ox1 = x1 + off, oy1 = y1 + off, ox2 = x2 + off, oy2 = y2 + off;
      ssc[r] = scv; slab[r] = lab;
      bx[r] = make_float4(x1, y1, x2, y2);
      so0[r] = ox1; so1[r] = oy1; so2[r] = ox2; so3[r] = oy2;
      sa[r] = (ox2 - ox1) * (oy2 - oy1);  // areas on offset boxes (ref exact)
    }
  }
  __syncthreads();

  // block 0 publishes the decode for k_nms
  if (c == 0) {
    sel_score[t] = ssc[t];
    sel_label[t] = slab[t];
    reinterpret_cast<float4*>(boxes)[t] = bx[t];
  }

  // mask column c: bit i of maskC[c*1024+j] = "box c*64+i suppresses box j"
  {
    int j = t;
    unsigned long long bits = 0ull;
    if (j < TOPK) {
      float x1j = so0[j], y1j = so1[j], x2j = so2[j], y2j = so3[j];
      float aj = sa[j];
      int i0 = c * 64;
      for (int ii = 0; ii < 64; ++ii) {
        int i = i0 + ii;                   // block-uniform: LDS broadcast
        if (i < TOPK && i < j) {
          float xx1 = fmaxf(so0[i], x1j);
          float yy1 = fmaxf(so1[i], y1j);
          float xx2 = fminf(so2[i], x2j);
          float yy2 = fminf(so3[i], y2j);
          float inter = fmaxf(1e-28f, xx2 - xx1) * fmaxf(1e-28f, yy2 - yy1);
          float uni = sa[i] + aj - inter + 1e-14f;
          float iou = inter / uni;         // IEEE division: bit-matches reference
          if (iou > 0.6f) bits |= (1ull << ii);
        }
      }
    }
    maskC[c * 1024 + j] = bits;
  }
}

// Triangle-only staging (68KB, 16 waves) + single-wave greedy + epilogue.
__launch_bounds__(1024)
__global__ void k_nms(const unsigned long long* __restrict__ maskC,
                      const float* __restrict__ sel_score, const int* __restrict__ sel_label,
                      const float* __restrict__ boxes,
                      const int* __restrict__ pW, const int* __restrict__ pH,
                      float* __restrict__ out) {
  __shared__ unsigned long long sm[136 * 64];   // 68KB: upper triangle
  __shared__ float ssc[1024];
  __shared__ unsigned long long kwS[16];
  __shared__ int pf[136], pg[136];
  const int t = threadIdx.x;
  const int lane = t & 63;

  if (t < 136) {
    int p = t, f = 0;
    while (p >= 16 - f) { p -= 16 - f; ++f; }
    pf[t] = f; pg[t] = f + p;
  }
  ssc[t] = (t < TOPK) ? sel_score[t] : 0.0f;
  __syncthreads();
  for (int i = t; i < 136 * 64; i += 1024) {
    int p = i >> 6, l = i & 63;
    sm[i] = maskC[pf[p] * 1024 + pg[p] * 64 + l];
  }
  __syncthreads();

  if (t < 64) {  // wave 0: greedy, serial only in suppressing kept boxes
    unsigned long long supp[16];
    #pragma unroll
    for (int f = 0; f < 16; ++f) supp[f] = 0ull;
    #pragma unroll
    for (int f = 0; f < 16; ++f) {
      unsigned long long ct = sm[TRI_IDX(f, f) * 64 + lane];
      int r = f * 64 + lane;
      unsigned long long valid = __ballot((r < TOPK) && (ssc[r] >= 0.05f));
      unsigned long long sup_any = __ballot(ct != 0ull);
      unsigned long long avail = valid & ~supp[f];
      unsigned long long kwf = 0ull;
      while (avail) {
        unsigned long long fs = avail & sup_any;
        if (!fs) { kwf |= avail; break; }      // rest suppress nobody: keep all
        int i = __ffsll((long long)fs) - 1;
        unsigned long long below = (1ull << i) - 1ull;
        kwf |= avail & below;                  // non-suppressors before i
        kwf |= (1ull << i);
        unsigned long long vict = __ballot(((ct >> i) & 1ull) != 0ull);
        avail &= ~vict;
        avail &= ~(below | (1ull << i));
      }
      if (lane == 0) kwS[f] = kwf;
      #pragma unroll
      for (int g = f + 1; g < 16; ++g)
        supp[g] |= __ballot((sm[TRI_IDX(f, g) * 64 + lane] & kwf) != 0ull);
    }
  }
  __syncthreads();

  float sw = (float)(*pW * 32);
  float sh = (float)(*pH * 32);
  const float4* b4 = reinterpret_cast<const float4*>(boxes);
  if (t < TOPK) {
    int r = t;
    bool kp = (kwS[r >> 6] >> (r & 63)) & 1ull;
    float m = kp ? 1.0f : 0.0f;
    float4 b = b4[r];
    float b0 = fminf(fmaxf(b.x / sw, 0.0f), 1.0f) * m;
    float b1 = fminf(fmaxf(b.y / sh, 0.0f), 1.0f) * m;
    float b2 = fminf(fmaxf(b.z / sw, 0.0f), 1.0f) * m;
    float b3 = fminf(fmaxf(b.w / sh, 0.0f), 1.0f) * m;
    out[r * 4 + 0] = b0; out[r * 4 + 1] = b1;
    out[r * 4 + 2] = b2; out[r * 4 + 3] = b3;
    out[TOPK * 4 + r] = ssc[r] * m;
    out[TOPK * 5 + r] = kp ? (float)sel_label[r] : -1.0f;
    out[TOPK * 6 + r] = m;
  }
}

extern "C" void kernel_launch(void* const* d_in, const int* in_sizes, int n_in,
                              void* d_out, int out_size, void* d_ws, size_t ws_size,
                              hipStream_t stream) {
  const float* cls = (const float*)d_in[0];
  const float* reg = (const float*)d_in[1];
  const float* asz = (const float*)d_in[2];
  const int* pH = (const int*)d_in[3];
  const int* pW = (const int*)d_in[4];
  int M = in_sizes[0] / NCLS;
  int A = in_sizes[2] / 2;

  char* ws = (char*)d_ws;
  size_t off = 0;
  auto alloc = [&](size_t bytes) { size_t o = off; off = (off + bytes + 255) & ~(size_t)255; return o; };
  size_t o_h1    = alloc(4096 * sizeof(unsigned));
  size_t o_cnt   = alloc(256);                      // gcount @ +0
  size_t zero_end = off;
  size_t o_cand  = alloc((size_t)CAND_CAP * sizeof(unsigned long long));
  size_t o_candp = alloc((size_t)CAND_CAP * sizeof(float4));
  size_t o_candl = alloc((size_t)CAND_CAP * sizeof(int));
  size_t o_sc    = alloc((size_t)M * sizeof(float));
  size_t o_lb    = alloc((size_t)M * sizeof(int));
  size_t o_ssc   = alloc(1024 * sizeof(float));
  size_t o_slb   = alloc(1024 * sizeof(int));
  size_t o_box   = alloc(1024 * 4 * sizeof(float));
  size_t o_mask  = alloc((size_t)16 * 1024 * sizeof(unsigned long long));
  (void)ws_size; (void)out_size; (void)n_in;

  int zwords = (int)(zero_end / 4);
  k_zero<<<(zwords + 255) / 256, 256, 0, stream>>>((unsigned*)ws, zwords);
  int nblk_score = (M * 4 + 1023) / 1024;
  k_score<<<nblk_score, 1024, 0, stream>>>(
      cls, (float*)(ws + o_sc), (int*)(ws + o_lb), (unsigned*)(ws + o_h1), M);
  int nblk_cmp = ((M + 3) / 4 + 1023) / 1024;
  k_compact<<<nblk_cmp, 1024, 0, stream>>>(
      (const unsigned*)(ws + o_h1), (const float*)(ws + o_sc),
      (const int*)(ws + o_lb), reg,
      (unsigned long long*)(ws + o_cand), (float4*)(ws + o_candp),
      (int*)(ws + o_candl), (unsigned*)(ws + o_cnt), M);
  k_maskr<<<16, 1024, 0, stream>>>(
      (const unsigned long long*)(ws + o_cand), (const float4*)(ws + o_candp),
      (const int*)(ws + o_candl), (const unsigned*)(ws + o_cnt),
      asz, pW, A,
      (float*)(ws + o_ssc), (int*)(ws + o_slb), (float*)(ws + o_box),
      (unsigned long long*)(ws + o_mask));
  k_nms<<<1, 1024, 0, stream>>>(
      (const unsigned long long*)(ws + o_mask),
      (const float*)(ws + o_ssc), (const int*)(ws + o_slb),
      (const float*)(ws + o_box), pW, pH, (float*)d_out);
}

// Round 20
// 72.652 us; speedup vs baseline: 1.0357x; 1.0357x over previous
//
#include <hip/hip_runtime.h>
#include <math.h>

#define NCLS 80
#define TOPK 1000
#define CAND_CAP 4096
#define TRI_IDX(f, g) ((f) * 16 - ((f) * ((f) - 1)) / 2 + ((g) - (f)))

// Correctly-rounded float sigmoid: matches numpy's 1/(1+np.exp(-x)) bit-for-bit.
__device__ __forceinline__ float sigmoid_np(float x) {
  float e = (float)exp(-(double)x);
  return 1.0f / (1.0f + e);
}
__device__ __forceinline__ float exp_np(float x) { return (float)exp((double)x); }

__device__ __forceinline__ unsigned fkey(float s) {
  unsigned u = __float_as_uint(s);
  return ((int)u < 0) ? ~u : (u | 0x80000000u);
}

// Scores are sigmoid(max of 80 logits) in (0.5, 1): float exponent constant,
// all ordering in the mantissa. 4096 bins on mantissa bits [22:11].
#define KEY_BASE 0xBF000000u
__device__ __forceinline__ unsigned kbin(unsigned key) { return (key >> 11) & 0xFFFu; }

// Wave-aggregated LDS histogram add: one atomic per distinct bin per wave.
__device__ __forceinline__ void agg_add(unsigned* h, unsigned bin, bool pred) {
  unsigned long long rem = __ballot(pred);
  const int lane = threadIdx.x & 63;
  while (rem) {
    int leader = __ffsll(rem) - 1;
    unsigned lb = (unsigned)__shfl((int)bin, leader, 64);
    unsigned long long m = __ballot(pred && bin == lb);
    if (lane == leader) atomicAdd(&h[lb], (unsigned)__popcll(m));
    rem &= ~m;
  }
}

__global__ void k_zero(unsigned* __restrict__ p, int nwords) {
  int i = blockIdx.x * 256 + threadIdx.x;
  if (i < nwords) p[i] = 0u;
}

// 4 lanes per anchor; argmax on raw logits; one exact sigmoid per anchor;
// per-block LDS hist of mantissa[22:11], nonzero bins merged to ghist1.
__launch_bounds__(1024)
__global__ void k_score(const float* __restrict__ cls, float* __restrict__ scores,
                        int* __restrict__ labels, unsigned* __restrict__ ghist1, int M) {
  __shared__ unsigned h1[4096];
  const int t = threadIdx.x;
  #pragma unroll
  for (int k = 0; k < 4; ++k) h1[t + 1024 * k] = 0u;
  __syncthreads();

  int gid = blockIdx.x * 1024 + t;
  int anchor = gid >> 2;
  int q = gid & 3;
  bool act = anchor < M;
  float lv[20];
  float best = -3.4e38f; int bc = 0;
  if (act) {
    const float4* row = reinterpret_cast<const float4*>(cls) + (size_t)anchor * (NCLS / 4);
    #pragma unroll
    for (int k = 0; k < 5; ++k) {
      float4 v = row[q + 4 * k];
      int cbase = (q + 4 * k) * 4;
      lv[4 * k + 0] = v.x; lv[4 * k + 1] = v.y; lv[4 * k + 2] = v.z; lv[4 * k + 3] = v.w;
      if (v.x > best) { best = v.x; bc = cbase + 0; }
      if (v.y > best) { best = v.y; bc = cbase + 1; }
      if (v.z > best) { best = v.z; bc = cbase + 2; }
      if (v.w > best) { best = v.w; bc = cbase + 3; }
    }
  } else {
    #pragma unroll
    for (int k = 0; k < 20; ++k) lv[k] = -3.4e38f;
  }
  #pragma unroll
  for (int d = 1; d < 4; d <<= 1) {
    float ob = __shfl_xor(best, d, 64);
    int oc = __shfl_xor(bc, d, 64);
    if (ob > best || (ob == best && oc < bc)) { best = ob; bc = oc; }
  }
  float s = sigmoid_np(best);
  float sp = s * (1.0f - s);
  float band = (s < 1.0f && sp > 0.0f) ? (4.8e-7f / sp) : 3.4e38f;  // 8 ulps margin
  float thresh = best - band;
  int cclose = 1 << 30;
  #pragma unroll
  for (int k = 0; k < 5; ++k) {
    #pragma unroll
    for (int j = 0; j < 4; ++j) {
      int c = (q + 4 * k) * 4 + j;
      if (lv[4 * k + j] >= thresh && c < cclose) cclose = c;
    }
  }
  #pragma unroll
  for (int d = 1; d < 4; d <<= 1) {
    int oc = __shfl_xor(cclose, d, 64);
    if (oc < cclose) cclose = oc;
  }
  int lab = bc;
  if (act && cclose < bc && q == 0) {  // rare exact fallback
    float bp = -1.0f; int bl = 0;
    for (int c = 0; c < NCLS; ++c) {
      float p = sigmoid_np(cls[(size_t)anchor * NCLS + c]);
      if (p > bp) { bp = p; bl = c; }
    }
    lab = bl;
  }
  unsigned key = fkey(s);
  if (act && q == 0) {
    scores[anchor] = s;
    labels[anchor] = lab;
  }
  agg_add(h1, kbin(key), act && q == 0 && key >= KEY_BASE);
  __syncthreads();
  #pragma unroll
  for (int k = 0; k < 4; ++k) {
    unsigned c = h1[t + 1024 * k];
    if (c) atomicAdd(&ghist1[t + 1024 * k], c);
  }
}

// Multi-block compact (R13: anything O(M) must be multi-block; R19: thin
// records — fat-record gathering cost more in this serial node than it saved).
__launch_bounds__(1024)
__global__ void k_compact(const unsigned* __restrict__ ghist1, const float* __restrict__ scores,
                          unsigned long long* __restrict__ cand, unsigned* __restrict__ gcount,
                          int M) {
  __shared__ unsigned chunks[1024];
  __shared__ int sB1;
  __shared__ unsigned wcnt[16];
  __shared__ unsigned sbase;
  const int t = threadIdx.x;
  const int lane = t & 63, wid = t >> 6;
  if (t == 0) sB1 = 0;

  unsigned hb0 = ghist1[4 * t], hb1 = ghist1[4 * t + 1],
           hb2 = ghist1[4 * t + 2], hb3 = ghist1[4 * t + 3];
  chunks[t] = hb0 + hb1 + hb2 + hb3;
  __syncthreads();
  for (int d = 1; d < 1024; d <<= 1) {
    unsigned v = chunks[t] + ((t + d < 1024) ? chunks[t + d] : 0u);
    __syncthreads(); chunks[t] = v; __syncthreads();
  }
  {
    unsigned ssc = chunks[t];
    unsigned ssn = (t + 1 < 1024) ? chunks[t + 1] : 0u;
    if (ssc >= (unsigned)TOPK && ssn < (unsigned)TOPK) {
      unsigned hb[4] = {hb0, hb1, hb2, hb3};
      unsigned run = ssn;
      for (int b = 3; b >= 0; --b) {
        run += hb[b];
        if (run >= (unsigned)TOPK) { sB1 = 4 * t + b; break; }
      }
    }
  }
  __syncthreads();
  const unsigned T = KEY_BASE + ((unsigned)sB1 << 11);

  int base = (blockIdx.x * 1024 + t) * 4;
  unsigned keys[4]; int idxs[4]; int np = 0;
  if (base + 3 < M) {
    float4 v = *reinterpret_cast<const float4*>(scores + base);
    unsigned kk[4] = {fkey(v.x), fkey(v.y), fkey(v.z), fkey(v.w)};
    #pragma unroll
    for (int j = 0; j < 4; ++j)
      if (kk[j] >= T) { keys[np] = kk[j]; idxs[np] = base + j; ++np; }
  } else {
    for (int i = base; i < M; ++i) {
      unsigned key = fkey(scores[i]);
      if (key >= T) { keys[np] = key; idxs[np] = i; ++np; }
    }
  }
  int sc = np;
  #pragma unroll
  for (int d = 1; d < 64; d <<= 1) {
    int o = __shfl_up(sc, d, 64);
    if (lane >= d) sc += o;
  }
  if (lane == 63) wcnt[wid] = (unsigned)sc;
  __syncthreads();
  if (t == 0) {
    unsigned acc = 0;
    for (int w = 0; w < 16; ++w) { unsigned v = wcnt[w]; wcnt[w] = acc; acc += v; }
    sbase = acc ? atomicAdd(gcount, acc) : 0u;
  }
  __syncthreads();
  unsigned pos = sbase + wcnt[wid] + (unsigned)(sc - np);
  for (int j = 0; j < np; ++j) {
    if (pos < (unsigned)CAND_CAP)
      cand[pos] = ((unsigned long long)keys[j] << 32) | (unsigned)(~(unsigned)idxs[j]);
    ++pos;
  }
}

// 16-block mask with replicated rank+decode (R17: mask divisions multi-CU;
// R19 fix: rank j-loop moved INSIDE the actv guard so fully-inactive waves
// of chunk 2 skip via execz instead of burning ~1100 iterations).
__launch_bounds__(1024)
__global__ void k_maskr(const unsigned long long* __restrict__ cand,
                        const unsigned* __restrict__ gcount,
                        const int* __restrict__ labels, const float* __restrict__ reg,
                        const float* __restrict__ asz, const int* __restrict__ pW, int A,
                        float* __restrict__ sel_score, int* __restrict__ sel_label,
                        float* __restrict__ boxes,
                        unsigned long long* __restrict__ maskC) {
  __shared__ unsigned long long ck[CAND_CAP];   // 32KB
  __shared__ float so0[1024], so1[1024], so2[1024], so3[1024], sa[1024];  // 20KB
  __shared__ float4 bx[1024];                   // 16KB
  __shared__ float ssc[1024]; __shared__ int slab[1024];  // 8KB
  const int t = threadIdx.x;
  const int c = blockIdx.x;

  ssc[t] = 0.0f; slab[t] = 0;
  so0[t] = 0.0f; so1[t] = 0.0f; so2[t] = 0.0f; so3[t] = 0.0f; sa[t] = 0.0f;
  unsigned n = *gcount; if (n > (unsigned)CAND_CAP) n = (unsigned)CAND_CAP;
  for (int i = t; i < (int)n; i += 1024) ck[i] = cand[i];
  __syncthreads();

  // rank + decode (replicated per block; j-loop exec-guarded)
  for (int cc = 0; cc < CAND_CAP; cc += 1024) {
    if ((unsigned)cc >= n) break;
    int cidx = cc + t;
    if ((unsigned)cidx < n) {
      unsigned long long my = ck[cidx];
      int r = 0;
      for (int j = 0; j < (int)n; ++j) r += (ck[j] > my);
      if (r < TOPK) {
        unsigned key = (unsigned)(my >> 32);
        unsigned u = (key & 0x80000000u) ? (key ^ 0x80000000u) : ~key;
        float scv = __uint_as_float(u);
        int idx = (int)(~(unsigned)my);
        int lab = labels[idx];
        int W = *pW;
        int a = idx % A;
        int cell = idx / A;
        int x = cell % W;
        int y = cell / W;
        float aw = asz[a * 2 + 0], ah = asz[a * 2 + 1];
        float ax = ((float)x + 0.5f) * 32.0f;
        float ay = ((float)y + 0.5f) * 32.0f;
        float4 rg = *reinterpret_cast<const float4*>(reg + (size_t)idx * 4);
        float offx = fminf(fmaxf(rg.x * aw, -32.0f), 32.0f);
        float offy = fminf(fmaxf(rg.y * ah, -32.0f), 32.0f);
        float cx = ax + offx, cy = ay + offy;
        const float SC = 4.135166556742356f;  // log(1000/16)
        float bw = aw * exp_np(fminf(rg.z, SC));
        float bh = ah * exp_np(fminf(rg.w, SC));
        float x1 = cx - 0.5f * bw, y1 = cy - 0.5f * bh;
        float x2 = cx + 0.5f * bw, y2 = cy + 0.5f * bh;
        float off = (float)lab * 100000.0f;
        float ox1 = x1 + off, oy1 = y1 + off, ox2 = x2 + off, oy2 = y2 + off;
        ssc[r] = scv; slab[r] = lab;
        bx[r] = make_float4(x1, y1, x2, y2);
        so0[r] = ox1; so1[r] = oy1; so2[r] = ox2; so3[r] = oy2;
        sa[r] = (ox2 - ox1) * (oy2 - oy1);  // areas on offset boxes (ref exact)
      }
    }
  }
  __syncthreads();

  // block 0 publishes the decode for k_nms
  if (c == 0) {
    sel_score[t] = ssc[t];
    sel_label[t] = slab[t];
    reinterpret_cast<float4*>(boxes)[t] = bx[t];
  }

  // mask column c: bit i of maskC[c*1024+j] = "box c*64+i suppresses box j"
  {
    int j = t;
    unsigned long long bits = 0ull;
    if (j < TOPK) {
      float x1j = so0[j], y1j = so1[j], x2j = so2[j], y2j = so3[j];
      float aj = sa[j];
      int i0 = c * 64;
      for (int ii = 0; ii < 64; ++ii) {
        int i = i0 + ii;                   // block-uniform: LDS broadcast
        if (i < TOPK && i < j) {
          float xx1 = fmaxf(so0[i], x1j);
          float yy1 = fmaxf(so1[i], y1j);
          float xx2 = fminf(so2[i], x2j);
          float yy2 = fminf(so3[i], y2j);
          float inter = fmaxf(1e-28f, xx2 - xx1) * fmaxf(1e-28f, yy2 - yy1);
          float uni = sa[i] + aj - inter + 1e-14f;
          float iou = inter / uni;         // IEEE division: bit-matches reference
          if (iou > 0.6f) bits |= (1ull << ii);
        }
      }
    }
    maskC[c * 1024 + j] = bits;
  }
}

// Triangle-only staging (68KB, 16 waves) + single-wave greedy + epilogue.
__launch_bounds__(1024)
__global__ void k_nms(const unsigned long long* __restrict__ maskC,
                      const float* __restrict__ sel_score, const int* __restrict__ sel_label,
                      const float* __restrict__ boxes,
                      const int* __restrict__ pW, const int* __restrict__ pH,
                      float* __restrict__ out) {
  __shared__ unsigned long long sm[136 * 64];   // 68KB: upper triangle
  __shared__ float ssc[1024];
  __shared__ unsigned long long kwS[16];
  __shared__ int pf[136], pg[136];
  const int t = threadIdx.x;
  const int lane = t & 63;

  if (t < 136) {
    int p = t, f = 0;
    while (p >= 16 - f) { p -= 16 - f; ++f; }
    pf[t] = f; pg[t] = f + p;
  }
  ssc[t] = (t < TOPK) ? sel_score[t] : 0.0f;
  __syncthreads();
  for (int i = t; i < 136 * 64; i += 1024) {
    int p = i >> 6, l = i & 63;
    sm[i] = maskC[pf[p] * 1024 + pg[p] * 64 + l];
  }
  __syncthreads();

  if (t < 64) {  // wave 0: greedy, serial only in suppressing kept boxes
    unsigned long long supp[16];
    #pragma unroll
    for (int f = 0; f < 16; ++f) supp[f] = 0ull;
    #pragma unroll
    for (int f = 0; f < 16; ++f) {
      unsigned long long ct = sm[TRI_IDX(f, f) * 64 + lane];
      int r = f * 64 + lane;
      unsigned long long valid = __ballot((r < TOPK) && (ssc[r] >= 0.05f));
      unsigned long long sup_any = __ballot(ct != 0ull);
      unsigned long long avail = valid & ~supp[f];
      unsigned long long kwf = 0ull;
      while (avail) {
        unsigned long long fs = avail & sup_any;
        if (!fs) { kwf |= avail; break; }      // rest suppress nobody: keep all
        int i = __ffsll((long long)fs) - 1;
        unsigned long long below = (1ull << i) - 1ull;
        kwf |= avail & below;                  // non-suppressors before i
        kwf |= (1ull << i);
        unsigned long long vict = __ballot(((ct >> i) & 1ull) != 0ull);
        avail &= ~vict;
        avail &= ~(below | (1ull << i));
      }
      if (lane == 0) kwS[f] = kwf;
      #pragma unroll
      for (int g = f + 1; g < 16; ++g)
        supp[g] |= __ballot((sm[TRI_IDX(f, g) * 64 + lane] & kwf) != 0ull);
    }
  }
  __syncthreads();

  float sw = (float)(*pW * 32);
  float sh = (float)(*pH * 32);
  const float4* b4 = reinterpret_cast<const float4*>(boxes);
  if (t < TOPK) {
    int r = t;
    bool kp = (kwS[r >> 6] >> (r & 63)) & 1ull;
    float m = kp ? 1.0f : 0.0f;
    float4 b = b4[r];
    float b0 = fminf(fmaxf(b.x / sw, 0.0f), 1.0f) * m;
    float b1 = fminf(fmaxf(b.y / sh, 0.0f), 1.0f) * m;
    float b2 = fminf(fmaxf(b.z / sw, 0.0f), 1.0f) * m;
    float b3 = fminf(fmaxf(b.w / sh, 0.0f), 1.0f) * m;
    out[r * 4 + 0] = b0; out[r * 4 + 1] = b1;
    out[r * 4 + 2] = b2; out[r * 4 + 3] = b3;
    out[TOPK * 4 + r] = ssc[r] * m;
    out[TOPK * 5 + r] = kp ? (float)sel_label[r] : -1.0f;
    out[TOPK * 6 + r] = m;
  }
}

extern "C" void kernel_launch(void* const* d_in, const int* in_sizes, int n_in,
                              void* d_out, int out_size, void* d_ws, size_t ws_size,
                              hipStream_t stream) {
  const float* cls = (const float*)d_in[0];
  const float* reg = (const float*)d_in[1];
  const float* asz = (const float*)d_in[2];
  const int* pH = (const int*)d_in[3];
  const int* pW = (const int*)d_in[4];
  int M = in_sizes[0] / NCLS;
  int A = in_sizes[2] / 2;

  char* ws = (char*)d_ws;
  size_t off = 0;
  auto alloc = [&](size_t bytes) { size_t o = off; off = (off + bytes + 255) & ~(size_t)255; return o; };
  size_t o_h1   = alloc(4096 * sizeof(unsigned));
  size_t o_cnt  = alloc(256);                      // gcount @ +0
  size_t zero_end = off;
  size_t o_cand = alloc((size_t)CAND_CAP * sizeof(unsigned long long));
  size_t o_sc   = alloc((size_t)M * sizeof(float));
  size_t o_lb   = alloc((size_t)M * sizeof(int));
  size_t o_ssc  = alloc(1024 * sizeof(float));
  size_t o_slb  = alloc(1024 * sizeof(int));
  size_t o_box  = alloc(1024 * 4 * sizeof(float));
  size_t o_mask = alloc((size_t)16 * 1024 * sizeof(unsigned long long));
  (void)ws_size; (void)out_size; (void)n_in;

  int zwords = (int)(zero_end / 4);
  k_zero<<<(zwords + 255) / 256, 256, 0, stream>>>((unsigned*)ws, zwords);
  int nblk_score = (M * 4 + 1023) / 1024;
  k_score<<<nblk_score, 1024, 0, stream>>>(
      cls, (float*)(ws + o_sc), (int*)(ws + o_lb), (unsigned*)(ws + o_h1), M);
  int nblk_cmp = ((M + 3) / 4 + 1023) / 1024;
  k_compact<<<nblk_cmp, 1024, 0, stream>>>(
      (const unsigned*)(ws + o_h1), (const float*)(ws + o_sc),
      (unsigned long long*)(ws + o_cand), (unsigned*)(ws + o_cnt), M);
  k_maskr<<<16, 1024, 0, stream>>>(
      (const unsigned long long*)(ws + o_cand), (const unsigned*)(ws + o_cnt),
      (const int*)(ws + o_lb), reg, asz, pW, A,
      (float*)(ws + o_ssc), (int*)(ws + o_slb), (float*)(ws + o_box),
      (unsigned long long*)(ws + o_mask));
  k_nms<<<1, 1024, 0, stream>>>(
      (const unsigned long long*)(ws + o_mask),
      (const float*)(ws + o_ssc), (const int*)(ws + o_slb),
      (const float*)(ws + o_box), pW, pH, (float*)d_out);
}

// Round 21
// 69.416 us; speedup vs baseline: 1.0840x; 1.0466x over previous
//
#include <hip/hip_runtime.h>
#include <math.h>

#define NCLS 80
#define TOPK 1000
#define CAND_CAP 4096
#define TRI_IDX(f, g) ((f) * 16 - ((f) * ((f) - 1)) / 2 + ((g) - (f)))

// Correctly-rounded float sigmoid: matches numpy's 1/(1+np.exp(-x)) bit-for-bit.
__device__ __forceinline__ float sigmoid_np(float x) {
  float e = (float)exp(-(double)x);
  return 1.0f / (1.0f + e);
}
__device__ __forceinline__ float exp_np(float x) { return (float)exp((double)x); }

__device__ __forceinline__ unsigned fkey(float s) {
  unsigned u = __float_as_uint(s);
  return ((int)u < 0) ? ~u : (u | 0x80000000u);
}

// Scores are sigmoid(max of 80 logits) in (0.5, 1): float exponent constant,
// all ordering in the mantissa. 4096 bins on mantissa bits [22:11].
#define KEY_BASE 0xBF000000u

// 4 lanes per anchor; argmax on raw logits; one exact sigmoid per anchor.
// No histogram here (R20->R21: hist moved into k_compact; k_zero node dropped).
// One thread zeroes gcount for k_compact (safe: nothing reads it until the
// next kernel boundary).
__launch_bounds__(1024)
__global__ void k_score(const float* __restrict__ cls, float* __restrict__ scores,
                        int* __restrict__ labels, unsigned* __restrict__ gcount, int M) {
  const int t = threadIdx.x;
  if (blockIdx.x == 0 && t == 0) *gcount = 0u;

  int gid = blockIdx.x * 1024 + t;
  int anchor = gid >> 2;
  int q = gid & 3;
  bool act = anchor < M;
  float lv[20];
  float best = -3.4e38f; int bc = 0;
  if (act) {
    const float4* row = reinterpret_cast<const float4*>(cls) + (size_t)anchor * (NCLS / 4);
    #pragma unroll
    for (int k = 0; k < 5; ++k) {
      float4 v = row[q + 4 * k];
      int cbase = (q + 4 * k) * 4;
      lv[4 * k + 0] = v.x; lv[4 * k + 1] = v.y; lv[4 * k + 2] = v.z; lv[4 * k + 3] = v.w;
      if (v.x > best) { best = v.x; bc = cbase + 0; }
      if (v.y > best) { best = v.y; bc = cbase + 1; }
      if (v.z > best) { best = v.z; bc = cbase + 2; }
      if (v.w > best) { best = v.w; bc = cbase + 3; }
    }
  } else {
    #pragma unroll
    for (int k = 0; k < 20; ++k) lv[k] = -3.4e38f;
  }
  #pragma unroll
  for (int d = 1; d < 4; d <<= 1) {
    float ob = __shfl_xor(best, d, 64);
    int oc = __shfl_xor(bc, d, 64);
    if (ob > best || (ob == best && oc < bc)) { best = ob; bc = oc; }
  }
  float s = sigmoid_np(best);
  float sp = s * (1.0f - s);
  float band = (s < 1.0f && sp > 0.0f) ? (4.8e-7f / sp) : 3.4e38f;  // 8 ulps margin
  float thresh = best - band;
  int cclose = 1 << 30;
  #pragma unroll
  for (int k = 0; k < 5; ++k) {
    #pragma unroll
    for (int j = 0; j < 4; ++j) {
      int c = (q + 4 * k) * 4 + j;
      if (lv[4 * k + j] >= thresh && c < cclose) cclose = c;
    }
  }
  #pragma unroll
  for (int d = 1; d < 4; d <<= 1) {
    int oc = __shfl_xor(cclose, d, 64);
    if (oc < cclose) cclose = oc;
  }
  int lab = bc;
  if (act && cclose < bc && q == 0) {  // rare exact fallback
    float bp = -1.0f; int bl = 0;
    for (int c = 0; c < NCLS; ++c) {
      float p = sigmoid_np(cls[(size_t)anchor * NCLS + c]);
      if (p > bp) { bp = p; bl = c; }
    }
    lab = bl;
  }
  if (act && q == 0) {
    scores[anchor] = s;
    labels[anchor] = lab;
  }
}

// Multi-block compact with SELF-BUILT histogram (R21: removes the k_zero node,
// k_score's hist phases, and all ghist1 global traffic; each block builds a
// private LDS hist of the full L2-resident score array, then derives T and
// compacts its own slice; one global atomic per block for the append base).
__launch_bounds__(1024)
__global__ void k_compact(const float* __restrict__ scores,
                          unsigned long long* __restrict__ cand, unsigned* __restrict__ gcount,
                          int M) {
  __shared__ unsigned hist[4096];
  __shared__ unsigned chunks[1024];
  __shared__ int sB1;
  __shared__ unsigned wcnt[16];
  __shared__ unsigned sbase;
  const int t = threadIdx.x;
  const int lane = t & 63, wid = t >> 6;
  const int M4 = M >> 2;
  const float4* s4 = reinterpret_cast<const float4*>(scores);
  if (t == 0) sB1 = 0;
  #pragma unroll
  for (int k = 0; k < 4; ++k) hist[t + 1024 * k] = 0u;
  __syncthreads();

  // ---- Phase A: private hist of mantissa bins over ALL scores ----
  for (int i = t; i < M4; i += 1024) {
    float4 v = s4[i];
    unsigned k0 = fkey(v.x), k1 = fkey(v.y), k2 = fkey(v.z), k3 = fkey(v.w);
    if (k0 >= KEY_BASE) atomicAdd(&hist[(k0 >> 11) & 0xFFFu], 1u);
    if (k1 >= KEY_BASE) atomicAdd(&hist[(k1 >> 11) & 0xFFFu], 1u);
    if (k2 >= KEY_BASE) atomicAdd(&hist[(k2 >> 11) & 0xFFFu], 1u);
    if (k3 >= KEY_BASE) atomicAdd(&hist[(k3 >> 11) & 0xFFFu], 1u);
  }
  for (int i = M4 * 4 + t; i < M; i += 1024) {
    unsigned k0 = fkey(scores[i]);
    if (k0 >= KEY_BASE) atomicAdd(&hist[(k0 >> 11) & 0xFFFu], 1u);
  }
  __syncthreads();

  // ---- Phase B: threshold bin via inclusive suffix scan over 4096 bins ----
  unsigned hb0 = hist[4 * t], hb1 = hist[4 * t + 1],
           hb2 = hist[4 * t + 2], hb3 = hist[4 * t + 3];
  chunks[t] = hb0 + hb1 + hb2 + hb3;
  __syncthreads();
  for (int d = 1; d < 1024; d <<= 1) {
    unsigned v = chunks[t] + ((t + d < 1024) ? chunks[t + d] : 0u);
    __syncthreads(); chunks[t] = v; __syncthreads();
  }
  {
    unsigned ssc = chunks[t];
    unsigned ssn = (t + 1 < 1024) ? chunks[t + 1] : 0u;
    if (ssc >= (unsigned)TOPK && ssn < (unsigned)TOPK) {
      unsigned hb[4] = {hb0, hb1, hb2, hb3};
      unsigned run = ssn;
      for (int b = 3; b >= 0; --b) {
        run += hb[b];
        if (run >= (unsigned)TOPK) { sB1 = 4 * t + b; break; }
      }
    }
  }
  __syncthreads();
  const unsigned T = KEY_BASE + ((unsigned)sB1 << 11);

  // ---- Phase C: compact own slice; one global atomic per block ----
  int base = (blockIdx.x * 1024 + t) * 4;
  unsigned keys[4]; int idxs[4]; int np = 0;
  if (base + 3 < M) {
    float4 v = *reinterpret_cast<const float4*>(scores + base);
    unsigned kk[4] = {fkey(v.x), fkey(v.y), fkey(v.z), fkey(v.w)};
    #pragma unroll
    for (int j = 0; j < 4; ++j)
      if (kk[j] >= T) { keys[np] = kk[j]; idxs[np] = base + j; ++np; }
  } else {
    for (int i = base; i < M; ++i) {
      unsigned key = fkey(scores[i]);
      if (key >= T) { keys[np] = key; idxs[np] = i; ++np; }
    }
  }
  int sc = np;
  #pragma unroll
  for (int d = 1; d < 64; d <<= 1) {
    int o = __shfl_up(sc, d, 64);
    if (lane >= d) sc += o;
  }
  if (lane == 63) wcnt[wid] = (unsigned)sc;
  __syncthreads();
  if (t == 0) {
    unsigned acc = 0;
    for (int w = 0; w < 16; ++w) { unsigned v = wcnt[w]; wcnt[w] = acc; acc += v; }
    sbase = acc ? atomicAdd(gcount, acc) : 0u;
  }
  __syncthreads();
  unsigned pos = sbase + wcnt[wid] + (unsigned)(sc - np);
  for (int j = 0; j < np; ++j) {
    if (pos < (unsigned)CAND_CAP)
      cand[pos] = ((unsigned long long)keys[j] << 32) | (unsigned)(~(unsigned)idxs[j]);
    ++pos;
  }
}

// 16-block mask with replicated rank+decode (R17: mask divisions multi-CU;
// R20: rank j-loop exec-guarded). Block 0 publishes sel_*/boxes for k_nms.
__launch_bounds__(1024)
__global__ void k_maskr(const unsigned long long* __restrict__ cand,
                        const unsigned* __restrict__ gcount,
                        const int* __restrict__ labels, const float* __restrict__ reg,
                        const float* __restrict__ asz, const int* __restrict__ pW, int A,
                        float* __restrict__ sel_score, int* __restrict__ sel_label,
                        float* __restrict__ boxes,
                        unsigned long long* __restrict__ maskC) {
  __shared__ unsigned long long ck[CAND_CAP];   // 32KB
  __shared__ float so0[1024], so1[1024], so2[1024], so3[1024], sa[1024];  // 20KB
  __shared__ float4 bx[1024];                   // 16KB
  __shared__ float ssc[1024]; __shared__ int slab[1024];  // 8KB
  const int t = threadIdx.x;
  const int c = blockIdx.x;

  ssc[t] = 0.0f; slab[t] = 0;
  so0[t] = 0.0f; so1[t] = 0.0f; so2[t] = 0.0f; so3[t] = 0.0f; sa[t] = 0.0f;
  unsigned n = *gcount; if (n > (unsigned)CAND_CAP) n = (unsigned)CAND_CAP;
  for (int i = t; i < (int)n; i += 1024) ck[i] = cand[i];
  __syncthreads();

  // rank + decode (replicated per block; j-loop exec-guarded)
  for (int cc = 0; cc < CAND_CAP; cc += 1024) {
    if ((unsigned)cc >= n) break;
    int cidx = cc + t;
    if ((unsigned)cidx < n) {
      unsigned long long my = ck[cidx];
      int r = 0;
      for (int j = 0; j < (int)n; ++j) r += (ck[j] > my);
      if (r < TOPK) {
        unsigned key = (unsigned)(my >> 32);
        unsigned u = (key & 0x80000000u) ? (key ^ 0x80000000u) : ~key;
        float scv = __uint_as_float(u);
        int idx = (int)(~(unsigned)my);
        int lab = labels[idx];
        int W = *pW;
        int a = idx % A;
        int cell = idx / A;
        int x = cell % W;
        int y = cell / W;
        float aw = asz[a * 2 + 0], ah = asz[a * 2 + 1];
        float ax = ((float)x + 0.5f) * 32.0f;
        float ay = ((float)y + 0.5f) * 32.0f;
        float4 rg = *reinterpret_cast<const float4*>(reg + (size_t)idx * 4);
        float offx = fminf(fmaxf(rg.x * aw, -32.0f), 32.0f);
        float offy = fminf(fmaxf(rg.y * ah, -32.0f), 32.0f);
        float cx = ax + offx, cy = ay + offy;
        const float SC = 4.135166556742356f;  // log(1000/16)
        float bw = aw * exp_np(fminf(rg.z, SC));
        float bh = ah * exp_np(fminf(rg.w, SC));
        float x1 = cx - 0.5f * bw, y1 = cy - 0.5f * bh;
        float x2 = cx + 0.5f * bw, y2 = cy + 0.5f * bh;
        float off = (float)lab * 100000.0f;
        float ox1 = x1 + off, oy1 = y1 + off, ox2 = x2 + off, oy2 = y2 + off;
        ssc[r] = scv; slab[r] = lab;
        bx[r] = make_float4(x1, y1, x2, y2);
        so0[r] = ox1; so1[r] = oy1; so2[r] = ox2; so3[r] = oy2;
        sa[r] = (ox2 - ox1) * (oy2 - oy1);  // areas on offset boxes (ref exact)
      }
    }
  }
  __syncthreads();

  // block 0 publishes the decode for k_nms
  if (c == 0) {
    sel_score[t] = ssc[t];
    sel_label[t] = slab[t];
    reinterpret_cast<float4*>(boxes)[t] = bx[t];
  }

  // mask column c: bit i of maskC[c*1024+j] = "box c*64+i suppresses box j"
  {
    int j = t;
    unsigned long long bits = 0ull;
    if (j < TOPK) {
      float x1j = so0[j], y1j = so1[j], x2j = so2[j], y2j = so3[j];
      float aj = sa[j];
      int i0 = c * 64;
      for (int ii = 0; ii < 64; ++ii) {
        int i = i0 + ii;                   // block-uniform: LDS broadcast
        if (i < TOPK && i < j) {
          float xx1 = fmaxf(so0[i], x1j);
          float yy1 = fmaxf(so1[i], y1j);
          float xx2 = fminf(so2[i], x2j);
          float yy2 = fminf(so3[i], y2j);
          float inter = fmaxf(1e-28f, xx2 - xx1) * fmaxf(1e-28f, yy2 - yy1);
          float uni = sa[i] + aj - inter + 1e-14f;
          float iou = inter / uni;         // IEEE division: bit-matches reference
          if (iou > 0.6f) bits |= (1ull << ii);
        }
      }
    }
    maskC[c * 1024 + j] = bits;
  }
}

// Triangle-only staging (68KB, 16 waves) + single-wave greedy + epilogue.
__launch_bounds__(1024)
__global__ void k_nms(const unsigned long long* __restrict__ maskC,
                      const float* __restrict__ sel_score, const int* __restrict__ sel_label,
                      const float* __restrict__ boxes,
                      const int* __restrict__ pW, const int* __restrict__ pH,
                      float* __restrict__ out) {
  __shared__ unsigned long long sm[136 * 64];   // 68KB: upper triangle
  __shared__ float ssc[1024];
  __shared__ unsigned long long kwS[16];
  __shared__ int pf[136], pg[136];
  const int t = threadIdx.x;
  const int lane = t & 63;

  if (t < 136) {
    int p = t, f = 0;
    while (p >= 16 - f) { p -= 16 - f; ++f; }
    pf[t] = f; pg[t] = f + p;
  }
  ssc[t] = (t < TOPK) ? sel_score[t] : 0.0f;
  __syncthreads();
  for (int i = t; i < 136 * 64; i += 1024) {
    int p = i >> 6, l = i & 63;
    sm[i] = maskC[pf[p] * 1024 + pg[p] * 64 + l];
  }
  __syncthreads();

  if (t < 64) {  // wave 0: greedy, serial only in suppressing kept boxes
    unsigned long long supp[16];
    #pragma unroll
    for (int f = 0; f < 16; ++f) supp[f] = 0ull;
    #pragma unroll
    for (int f = 0; f < 16; ++f) {
      unsigned long long ct = sm[TRI_IDX(f, f) * 64 + lane];
      int r = f * 64 + lane;
      unsigned long long valid = __ballot((r < TOPK) && (ssc[r] >= 0.05f));
      unsigned long long sup_any = __ballot(ct != 0ull);
      unsigned long long avail = valid & ~supp[f];
      unsigned long long kwf = 0ull;
      while (avail) {
        unsigned long long fs = avail & sup_any;
        if (!fs) { kwf |= avail; break; }      // rest suppress nobody: keep all
        int i = __ffsll((long long)fs) - 1;
        unsigned long long below = (1ull << i) - 1ull;
        kwf |= avail & below;                  // non-suppressors before i
        kwf |= (1ull << i);
        unsigned long long vict = __ballot(((ct >> i) & 1ull) != 0ull);
        avail &= ~vict;
        avail &= ~(below | (1ull << i));
      }
      if (lane == 0) kwS[f] = kwf;
      #pragma unroll
      for (int g = f + 1; g < 16; ++g)
        supp[g] |= __ballot((sm[TRI_IDX(f, g) * 64 + lane] & kwf) != 0ull);
    }
  }
  __syncthreads();

  float sw = (float)(*pW * 32);
  float sh = (float)(*pH * 32);
  const float4* b4 = reinterpret_cast<const float4*>(boxes);
  if (t < TOPK) {
    int r = t;
    bool kp = (kwS[r >> 6] >> (r & 63)) & 1ull;
    float m = kp ? 1.0f : 0.0f;
    float4 b = b4[r];
    float b0 = fminf(fmaxf(b.x / sw, 0.0f), 1.0f) * m;
    float b1 = fminf(fmaxf(b.y / sh, 0.0f), 1.0f) * m;
    float b2 = fminf(fmaxf(b.z / sw, 0.0f), 1.0f) * m;
    float b3 = fminf(fmaxf(b.w / sh, 0.0f), 1.0f) * m;
    out[r * 4 + 0] = b0; out[r * 4 + 1] = b1;
    out[r * 4 + 2] = b2; out[r * 4 + 3] = b3;
    out[TOPK * 4 + r] = ssc[r] * m;
    out[TOPK * 5 + r] = kp ? (float)sel_label[r] : -1.0f;
    out[TOPK * 6 + r] = m;
  }
}

extern "C" void kernel_launch(void* const* d_in, const int* in_sizes, int n_in,
                              void* d_out, int out_size, void* d_ws, size_t ws_size,
                              hipStream_t stream) {
  const float* cls = (const float*)d_in[0];
  const float* reg = (const float*)d_in[1];
  const float* asz = (const float*)d_in[2];
  const int* pH = (const int*)d_in[3];
  const int* pW = (const int*)d_in[4];
  int M = in_sizes[0] / NCLS;
  int A = in_sizes[2] / 2;

  char* ws = (char*)d_ws;
  size_t off = 0;
  auto alloc = [&](size_t bytes) { size_t o = off; off = (off + bytes + 255) & ~(size_t)255; return o; };
  size_t o_cnt  = alloc(256);                      // gcount @ +0
  size_t o_cand = alloc((size_t)CAND_CAP * sizeof(unsigned long long));
  size_t o_sc   = alloc((size_t)M * sizeof(float));
  size_t o_lb   = alloc((size_t)M * sizeof(int));
  size_t o_ssc  = alloc(1024 * sizeof(float));
  size_t o_slb  = alloc(1024 * sizeof(int));
  size_t o_box  = alloc(1024 * 4 * sizeof(float));
  size_t o_mask = alloc((size_t)16 * 1024 * sizeof(unsigned long long));
  (void)ws_size; (void)out_size; (void)n_in;

  int nblk_score = (M * 4 + 1023) / 1024;
  k_score<<<nblk_score, 1024, 0, stream>>>(
      cls, (float*)(ws + o_sc), (int*)(ws + o_lb), (unsigned*)(ws + o_cnt), M);
  int nblk_cmp = ((M + 3) / 4 + 1023) / 1024;
  k_compact<<<nblk_cmp, 1024, 0, stream>>>(
      (const float*)(ws + o_sc),
      (unsigned long long*)(ws + o_cand), (unsigned*)(ws + o_cnt), M);
  k_maskr<<<16, 1024, 0, stream>>>(
      (const unsigned long long*)(ws + o_cand), (const unsigned*)(ws + o_cnt),
      (const int*)(ws + o_lb), reg, asz, pW, A,
      (float*)(ws + o_ssc), (int*)(ws + o_slb), (float*)(ws + o_box),
      (unsigned long long*)(ws + o_mask));
  k_nms<<<1, 1024, 0, stream>>>(
      (const unsigned long long*)(ws + o_mask),
      (const float*)(ws + o_ssc), (const int*)(ws + o_slb),
      (const float*)(ws + o_box), pW, pH, (float*)d_out);
}